// Round 17
// baseline (61.756 us; speedup 1.0000x reference)
//
#include <hip/hip_runtime.h>

// Grouped conv 3x3 SAME, NHWC fp32 -> bf16 MFMA. Single kernel.
// R16 = R15 + weights folded in: each thread loads its 18 f32 weight frags
// (L2-served) and converts in-reg at startup, overlapped with prologue DMA.
// Pipeline per iter: vmcnt(4)+lgkm(0)+barrier; cvt F->bf16 ring; DMA next row;
// 18 bf16 ds_read + 36 MFMA; 4 coalesced f32x4 stores (stay in flight).
#define NG 8
#define PC 32
#define FC 64
#define HH 56
#define WW 56
#define CIN 256
#define COUT 512
#define NB 16
#define SL 66                 // bf16 w slots: w_in = slot-1 in [-1,64]
#define PLANE (SL * 64)       // 4224 B per bf16 plane
#define NPL 5                 // bf16 ring planes
#define PLF (64 * 128)        // 8192 B per f32 plane (64 slots x 32ch x 4B)
#define HCH 7

typedef __bf16 bf16x8 __attribute__((ext_vector_type(8)));
typedef float f32x4 __attribute__((ext_vector_type(4)));

static __device__ __forceinline__ void dma16(const void* gsrc, void* lds) {
    typedef const __attribute__((address_space(1))) unsigned int* gp_t;
    typedef __attribute__((address_space(3))) unsigned int* lp_t;
    __builtin_amdgcn_global_load_lds((gp_t)gsrc, (lp_t)lds, 16, 0, 0);
}

static __device__ __forceinline__ bf16x8 cvt8(f32x4 a, f32x4 b) {
    bf16x8 r;
    r[0] = (__bf16)a[0]; r[1] = (__bf16)a[1]; r[2] = (__bf16)a[2]; r[3] = (__bf16)a[3];
    r[4] = (__bf16)b[0]; r[5] = (__bf16)b[1]; r[6] = (__bf16)b[2]; r[7] = (__bf16)b[3];
    return r;
}

static __device__ __forceinline__ int swz(int loc) {       // bf16 plane (R7)
    return loc ^ (((loc >> 7) & 3) << 4);
}
static __device__ __forceinline__ int swz32(int loc) {     // f32 plane
    return loc ^ (((loc >> 7) & 7) << 4);
}

__global__ __launch_bounds__(256, 4)
void groupconv_one_kernel(const float* __restrict__ x,
                          const float* __restrict__ krn,
                          const float* __restrict__ bias,
                          float* __restrict__ out) {
    const int b   = blockIdx.x;
    const int g   = b & 7;
    const int hcb = (b >> 3) & 7;
    const int n   = b >> 6;
    const int h0  = hcb * HCH;

    const int tid  = threadIdx.x;
    const int wave = tid >> 6;
    const int lane = tid & 63;
    const int lo = lane & 15;
    const int hi = lane >> 4;
    const int p0 = hi * 8;
    const int fm  = (wave >> 1) * 32;
    const int wnb = (wave & 1) * 32;

    __shared__ __align__(16) unsigned char lds[2 * PLF + NPL * PLANE];  // 37504 B
    unsigned char* const F0 = lds;
    unsigned char* const F1 = lds + PLF;
    unsigned char* const Bb = lds + 2 * PLF;

    // ---- DMA granule mapping (f32 planes): linear o holds logical swz32(o) ----
    const int o0 = tid * 16,        o1 = (tid + 256) * 16;
    const int l0 = swz32(o0),       l1 = swz32(o1);
    const int s0 = l0 >> 7,         s1 = l1 >> 7;
    const int q0 = (l0 >> 4) & 7,   q1 = (l1 >> 4) & 7;
    const bool ok0 = (s0 >= 1 && s0 <= 56);
    const bool ok1 = (s1 >= 1 && s1 <= 56);
    const float* xg = x + ((size_t)n * HH * WW) * CIN + g * PC;
    const size_t off0 = (size_t)(s0 - 1) * CIN + q0 * 4;   // + r*WW*CIN
    const size_t off1 = (size_t)(s1 - 1) * CIN + q1 * 4;

    // ---- cvt mapping: thread -> bf16 granule (slot sc, octet qc) ----
    const int sc  = tid >> 2;          // 0..63
    const int qc  = tid & 3;
    const int frd = swz32(sc * 128 + qc * 32);     // f32 lo-quad read addr
    const int bwr = swz(sc * 64 + qc * 16);        // bf16 write addr

#define STAGE(r_, Fdst)                                                         \
    do {                                                                        \
        const int r__ = (r_);                                                   \
        if ((unsigned)r__ < HH) {                                               \
            const float* rowp__ = xg + (size_t)r__ * WW * CIN;                  \
            if (ok0) dma16(rowp__ + off0, (Fdst) + wave * 1024);                \
            if (ok1) dma16(rowp__ + off1, (Fdst) + 4096 + wave * 1024);         \
        } else {                                                                \
            if (ok0) *reinterpret_cast<f32x4*>((Fdst) + o0) = (f32x4)0.f;       \
            if (ok1) *reinterpret_cast<f32x4*>((Fdst) + o1) = (f32x4)0.f;       \
        }                                                                       \
    } while (0)

#define CVTROW(Fsrc, Bdst)                                                      \
    do {                                                                        \
        f32x4 a__  = *reinterpret_cast<const f32x4*>((Fsrc) + frd);             \
        f32x4 b2__ = *reinterpret_cast<const f32x4*>((Fsrc) + (frd ^ 16));      \
        *reinterpret_cast<bf16x8*>((Bdst) + bwr) = cvt8(a__, b2__);             \
    } while (0)

    // ---- issue prologue DMAs FIRST (critical path), then weight loads ----
    STAGE(h0 - 1, F0);
    STAGE(h0,     F1);

    // weights f32 [g][tap][p][f] -> in-reg bf16 frags (A-operand: M=filters).
    // 144 scalar loads/thread; lanes coalesce over f; L2-served after first touch.
    bf16x8 bfr[9][2];
    {
        const float* kg = krn + (size_t)g * (9 * PC * FC);
#pragma unroll
        for (int t = 0; t < 9; ++t)
#pragma unroll
            for (int mi = 0; mi < 2; ++mi) {
                const float* kp = kg + ((size_t)t * PC + p0) * FC + (fm + mi * 16 + lo);
                bf16x8 r;
#pragma unroll
                for (int pp = 0; pp < 8; ++pp)
                    r[pp] = (__bf16)kp[(size_t)pp * FC];
                bfr[t][mi] = r;
            }
    }

    // ---- one-time zeros: invalid F granules (both planes); B slots 57..65 ----
    if (!ok0) { *reinterpret_cast<f32x4*>(F0 + o0) = (f32x4)0.f;
                *reinterpret_cast<f32x4*>(F1 + o0) = (f32x4)0.f; }
    if (!ok1) { *reinterpret_cast<f32x4*>(F0 + o1) = (f32x4)0.f;
                *reinterpret_cast<f32x4*>(F1 + o1) = (f32x4)0.f; }
    if (tid < 180) {
        const int q  = tid & 3;
        const int sq = tid >> 2;        // 0..44
        const int pl = sq / 9;
        const int s  = 57 + (sq % 9);
        *reinterpret_cast<bf16x8*>(Bb + pl * PLANE + swz(s * 64 + q * 16)) =
            (bf16x8)(__bf16)0.f;
    }

    // ---- prologue: build B[0..2] = rows h0-1..h0+1; leave F0 = row h0+2 ----
    asm volatile("s_waitcnt vmcnt(0) lgkmcnt(0)\n\ts_barrier" ::: "memory");
    CVTROW(F0, Bb + 0 * PLANE);
    CVTROW(F1, Bb + 1 * PLANE);
    asm volatile("s_waitcnt lgkmcnt(0)\n\ts_barrier" ::: "memory");
    STAGE(h0 + 1, F0);
    asm volatile("s_waitcnt vmcnt(0) lgkmcnt(0)\n\ts_barrier" ::: "memory");
    CVTROW(F0, Bb + 2 * PLANE);
    asm volatile("s_waitcnt lgkmcnt(0)\n\ts_barrier" ::: "memory");
    STAGE(h0 + 2, F0);

    float4 bvv[2];
#pragma unroll
    for (int mi = 0; mi < 2; ++mi)
        bvv[mi] = *reinterpret_cast<const float4*>(bias + g * FC + fm + mi * 16 + hi * 4);

    float* const outg = out + ((size_t)n * HH * WW) * COUT + g * FC;

#pragma unroll
    for (int i = 0; i < HCH; ++i) {
        const int h = h0 + i;

        // one barrier/iter: i==0 drains prologue DMA; else vmcnt(4) = last
        // iter's 4 stores (newest) -> DMA(i-1) complete; stores stay in flight.
        if (i == 0)
            asm volatile("s_waitcnt vmcnt(0) lgkmcnt(0)\n\ts_barrier" ::: "memory");
        else
            asm volatile("s_waitcnt vmcnt(4) lgkmcnt(0)\n\ts_barrier" ::: "memory");

        // cvt row h+2 (F[i&1]) -> bf16 plane (i+3)%5
        if (i <= HCH - 2) {
            const unsigned char* Fsrc = (i & 1) ? F1 : F0;
            CVTROW(Fsrc, Bb + ((i + 3) % NPL) * PLANE);
        }
        // DMA row h+3 -> F[(i+1)&1] (consumed by cvt at iter i+1)
        if (i <= HCH - 3) {
            unsigned char* Fdst = ((i + 1) & 1) ? F1 : F0;
            STAGE(h + 3, Fdst);
        }

        // compute row h: planes (i+kh)%5, 18 ds_read + 36 MFMA (R7-verified)
        f32x4 acc[2][2];
#pragma unroll
        for (int mi = 0; mi < 2; ++mi)
#pragma unroll
            for (int nj = 0; nj < 2; ++nj) acc[mi][nj] = (f32x4)0.f;

#pragma unroll
        for (int kh = 0; kh < 3; ++kh) {
            const unsigned char* plb = Bb + ((i + kh) % NPL) * PLANE;
#pragma unroll
            for (int kw = 0; kw < 3; ++kw) {
                const int t = kh * 3 + kw;
                bf16x8 bx[2];
#pragma unroll
                for (int nj = 0; nj < 2; ++nj) {
                    const int ss = wnb + nj * 16 + lo + kw;
                    bx[nj] = *reinterpret_cast<const bf16x8*>(plb + swz(ss * 64 + hi * 16));
                }
#pragma unroll
                for (int mi = 0; mi < 2; ++mi)
#pragma unroll
                    for (int nj = 0; nj < 2; ++nj)
                        acc[mi][nj] = __builtin_amdgcn_mfma_f32_16x16x32_bf16(
                            bfr[t][mi], bx[nj], acc[mi][nj], 0, 0, 0);
            }
        }

        // store row h: exactly 4 store instructions per wave (vmcnt accounting)
        float* const orow = outg + ((size_t)h * WW) * COUT;
#pragma unroll
        for (int mi = 0; mi < 2; ++mi) {
            const int f0 = fm + mi * 16 + hi * 4;
#pragma unroll
            for (int nj = 0; nj < 2; ++nj) {
                const int w = wnb + nj * 16 + lo;
                if (w < WW) {
                    f32x4 oo = acc[mi][nj];
                    oo[0] += bvv[mi].x; oo[1] += bvv[mi].y;
                    oo[2] += bvv[mi].z; oo[3] += bvv[mi].w;
                    *reinterpret_cast<f32x4*>(orow + (size_t)w * COUT + f0) = oo;
                }
            }
        }
    }
#undef STAGE
#undef CVTROW
}

// ---------------- launcher ----------------
extern "C" void kernel_launch(void* const* d_in, const int* in_sizes, int n_in,
                              void* d_out, int out_size, void* d_ws, size_t ws_size,
                              hipStream_t stream) {
    const float* x    = (const float*)d_in[0];
    const float* krn  = (const float*)d_in[1];
    const float* bias = (const float*)d_in[2];
    float* out = (float*)d_out;

    const int blocks = NB * 8 * NG;  // 1024
    groupconv_one_kernel<<<blocks, 256, 0, stream>>>(x, krn, bias, out);
}

// Round 18
// 36.518 us; speedup vs baseline: 1.6911x; 1.6911x over previous
//
#include <hip/hip_runtime.h>

// Grouped conv 3x3 SAME, NHWC fp32 -> bf16 MFMA. Single kernel.
// R17 = R15 main loop (41.4us, verified) + in-kernel weight transpose:
// coalesced f32x4 coop-load of group weights -> LDS scratch [t][f][p] bf16
// (granule-XOR by fq to break write conflicts) -> per-thread frag readback.
// Replaces the cvt_w kernel + workspace + inter-kernel dependency.
#define NG 8
#define PC 32
#define FC 64
#define HH 56
#define WW 56
#define CIN 256
#define COUT 512
#define NB 16
#define SL 66                 // bf16 w slots: w_in = slot-1 in [-1,64]
#define PLANE (SL * 64)       // 4224 B per bf16 plane
#define NPL 5                 // bf16 ring planes
#define PLF (64 * 128)        // 8192 B per f32 plane
#define HCH 7

typedef __bf16 bf16x8 __attribute__((ext_vector_type(8)));
typedef float f32x4 __attribute__((ext_vector_type(4)));

static __device__ __forceinline__ void dma16(const void* gsrc, void* lds) {
    typedef const __attribute__((address_space(1))) unsigned int* gp_t;
    typedef __attribute__((address_space(3))) unsigned int* lp_t;
    __builtin_amdgcn_global_load_lds((gp_t)gsrc, (lp_t)lds, 16, 0, 0);
}

static __device__ __forceinline__ bf16x8 cvt8(f32x4 a, f32x4 b) {
    bf16x8 r;
    r[0] = (__bf16)a[0]; r[1] = (__bf16)a[1]; r[2] = (__bf16)a[2]; r[3] = (__bf16)a[3];
    r[4] = (__bf16)b[0]; r[5] = (__bf16)b[1]; r[6] = (__bf16)b[2]; r[7] = (__bf16)b[3];
    return r;
}

static __device__ __forceinline__ int swz(int loc) {       // bf16 plane (R7)
    return loc ^ (((loc >> 7) & 3) << 4);
}
static __device__ __forceinline__ int swz32(int loc) {     // f32 plane
    return loc ^ (((loc >> 7) & 7) << 4);
}

__global__ __launch_bounds__(256, 4)
void groupconv_onew_kernel(const float* __restrict__ x,
                           const float* __restrict__ krn,
                           const float* __restrict__ bias,
                           float* __restrict__ out) {
    const int b   = blockIdx.x;
    const int g   = b & 7;
    const int hcb = (b >> 3) & 7;
    const int n   = b >> 6;
    const int h0  = hcb * HCH;

    const int tid  = threadIdx.x;
    const int wave = tid >> 6;
    const int lane = tid & 63;
    const int lo = lane & 15;
    const int hi = lane >> 4;
    const int p0 = hi * 8;
    const int fm  = (wave >> 1) * 32;
    const int wnb = (wave & 1) * 32;

    __shared__ __align__(16) unsigned char lds[2 * PLF + NPL * PLANE];  // 37504 B
    unsigned char* const F0 = lds;
    unsigned char* const F1 = lds + PLF;
    unsigned char* const Bb = lds + 2 * PLF;

    // ================= weight phase (prologue-only; scratch = lds) =========
    // Wlds layout: 16B granule (t, f, pq) at byte (t*64+f)*64 + (pq ^ (f>>2 & 3))*16
    // Coop load: u = tid + k*256, k<18 -> fq=u&15, p=(u>>4)&31, t=u>>9.
    // Global read: krn + g*18432 + (t*32+p)*64 + fq*4  (lanes -> contiguous 1KB).
    {
        const float* kg = krn + (size_t)g * (9 * PC * FC);
#pragma unroll
        for (int k = 0; k < 18; ++k) {
            const int u  = tid + k * 256;
            const int fq = u & 15;
            const int p  = (u >> 4) & 31;
            const int t  = u >> 9;
            f32x4 v = *reinterpret_cast<const f32x4*>(kg + ((size_t)t * PC + p) * FC + fq * 4);
            const int gr = (p >> 3) ^ (fq & 3);     // granule XOR (write-conflict fix)
            __bf16* wp = reinterpret_cast<__bf16*>(
                lds + ((t * 64 + fq * 4) * 64) + gr * 16 + (p & 7) * 2);
            // f = fq*4 + j -> +j*64 bytes
#pragma unroll
            for (int j = 0; j < 4; ++j)
                wp[j * 32] = (__bf16)v[j];          // 32 bf16 = 64 B row stride
        }
    }
    __syncthreads();

    // frag readback: f = fm+mi*16+lo, granule = hi ^ ((lo>>2)&3)
    bf16x8 bfr[9][2];
    {
        const int gx = hi ^ ((lo >> 2) & 3);
#pragma unroll
        for (int t = 0; t < 9; ++t)
#pragma unroll
            for (int mi = 0; mi < 2; ++mi) {
                const int f = fm + mi * 16 + lo;
                bfr[t][mi] = *reinterpret_cast<const bf16x8*>(
                    lds + (t * 64 + f) * 64 + gx * 16);
            }
    }
    __syncthreads();   // all frag reads done before scratch is overwritten
    // ================= end weight phase ====================================

    // ---- DMA granule mapping (f32 planes): linear o holds logical swz32(o) ----
    const int o0 = tid * 16,        o1 = (tid + 256) * 16;
    const int l0 = swz32(o0),       l1 = swz32(o1);
    const int s0 = l0 >> 7,         s1 = l1 >> 7;
    const int q0 = (l0 >> 4) & 7,   q1 = (l1 >> 4) & 7;
    const bool ok0 = (s0 >= 1 && s0 <= 56);
    const bool ok1 = (s1 >= 1 && s1 <= 56);
    const float* xg = x + ((size_t)n * HH * WW) * CIN + g * PC;
    const size_t off0 = (size_t)(s0 - 1) * CIN + q0 * 4;   // + r*WW*CIN
    const size_t off1 = (size_t)(s1 - 1) * CIN + q1 * 4;

    // ---- cvt mapping: thread -> bf16 granule (slot sc, octet qc) ----
    const int sc  = tid >> 2;          // 0..63
    const int qc  = tid & 3;
    const int frd = swz32(sc * 128 + qc * 32);     // f32 lo-quad read addr
    const int bwr = swz(sc * 64 + qc * 16);        // bf16 write addr

    // ---- one-time zeros: invalid F granules (both planes); B slots 57..65 ----
    if (!ok0) { *reinterpret_cast<f32x4*>(F0 + o0) = (f32x4)0.f;
                *reinterpret_cast<f32x4*>(F1 + o0) = (f32x4)0.f; }
    if (!ok1) { *reinterpret_cast<f32x4*>(F0 + o1) = (f32x4)0.f;
                *reinterpret_cast<f32x4*>(F1 + o1) = (f32x4)0.f; }
    if (tid < 180) {
        const int q  = tid & 3;
        const int sq = tid >> 2;        // 0..44
        const int pl = sq / 9;
        const int s  = 57 + (sq % 9);
        *reinterpret_cast<bf16x8*>(Bb + pl * PLANE + swz(s * 64 + q * 16)) =
            (bf16x8)(__bf16)0.f;
    }

#define STAGE(r_, Fdst)                                                         \
    do {                                                                        \
        const int r__ = (r_);                                                   \
        if ((unsigned)r__ < HH) {                                               \
            const float* rowp__ = xg + (size_t)r__ * WW * CIN;                  \
            if (ok0) dma16(rowp__ + off0, (Fdst) + wave * 1024);                \
            if (ok1) dma16(rowp__ + off1, (Fdst) + 4096 + wave * 1024);         \
        } else {                                                                \
            if (ok0) *reinterpret_cast<f32x4*>((Fdst) + o0) = (f32x4)0.f;       \
            if (ok1) *reinterpret_cast<f32x4*>((Fdst) + o1) = (f32x4)0.f;       \
        }                                                                       \
    } while (0)

#define CVTROW(Fsrc, Bdst)                                                      \
    do {                                                                        \
        f32x4 a__  = *reinterpret_cast<const f32x4*>((Fsrc) + frd);             \
        f32x4 b2__ = *reinterpret_cast<const f32x4*>((Fsrc) + (frd ^ 16));      \
        *reinterpret_cast<bf16x8*>((Bdst) + bwr) = cvt8(a__, b2__);             \
    } while (0)

    // ---- prologue: build B[0..2] = rows h0-1..h0+1; leave F0 = row h0+2 ----
    STAGE(h0 - 1, F0);
    STAGE(h0,     F1);
    asm volatile("s_waitcnt vmcnt(0) lgkmcnt(0)\n\ts_barrier" ::: "memory");
    CVTROW(F0, Bb + 0 * PLANE);
    CVTROW(F1, Bb + 1 * PLANE);
    asm volatile("s_waitcnt lgkmcnt(0)\n\ts_barrier" ::: "memory");
    STAGE(h0 + 1, F0);
    asm volatile("s_waitcnt vmcnt(0) lgkmcnt(0)\n\ts_barrier" ::: "memory");
    CVTROW(F0, Bb + 2 * PLANE);
    asm volatile("s_waitcnt lgkmcnt(0)\n\ts_barrier" ::: "memory");
    STAGE(h0 + 2, F0);

    float4 bvv[2];
#pragma unroll
    for (int mi = 0; mi < 2; ++mi)
        bvv[mi] = *reinterpret_cast<const float4*>(bias + g * FC + fm + mi * 16 + hi * 4);

    float* const outg = out + ((size_t)n * HH * WW) * COUT + g * FC;

#pragma unroll
    for (int i = 0; i < HCH; ++i) {
        const int h = h0 + i;

        // one barrier/iter: i==0 drains prologue DMA; else vmcnt(4) = last
        // iter's 4 stores (newest) -> DMA(i-1) complete; stores stay in flight.
        if (i == 0)
            asm volatile("s_waitcnt vmcnt(0) lgkmcnt(0)\n\ts_barrier" ::: "memory");
        else
            asm volatile("s_waitcnt vmcnt(4) lgkmcnt(0)\n\ts_barrier" ::: "memory");

        // cvt row h+2 (F[i&1]) -> bf16 plane (i+3)%5
        if (i <= HCH - 2) {
            const unsigned char* Fsrc = (i & 1) ? F1 : F0;
            CVTROW(Fsrc, Bb + ((i + 3) % NPL) * PLANE);
        }
        // DMA row h+3 -> F[(i+1)&1] (consumed by cvt at iter i+1)
        if (i <= HCH - 3) {
            unsigned char* Fdst = ((i + 1) & 1) ? F1 : F0;
            STAGE(h + 3, Fdst);
        }

        // compute row h: planes (i+kh)%5, 18 ds_read + 36 MFMA (R7-verified)
        f32x4 acc[2][2];
#pragma unroll
        for (int mi = 0; mi < 2; ++mi)
#pragma unroll
            for (int nj = 0; nj < 2; ++nj) acc[mi][nj] = (f32x4)0.f;

#pragma unroll
        for (int kh = 0; kh < 3; ++kh) {
            const unsigned char* plb = Bb + ((i + kh) % NPL) * PLANE;
#pragma unroll
            for (int kw = 0; kw < 3; ++kw) {
                const int t = kh * 3 + kw;
                bf16x8 bx[2];
#pragma unroll
                for (int nj = 0; nj < 2; ++nj) {
                    const int ss = wnb + nj * 16 + lo + kw;
                    bx[nj] = *reinterpret_cast<const bf16x8*>(plb + swz(ss * 64 + hi * 16));
                }
#pragma unroll
                for (int mi = 0; mi < 2; ++mi)
#pragma unroll
                    for (int nj = 0; nj < 2; ++nj)
                        acc[mi][nj] = __builtin_amdgcn_mfma_f32_16x16x32_bf16(
                            bfr[t][mi], bx[nj], acc[mi][nj], 0, 0, 0);
            }
        }

        // store row h: exactly 4 store instructions per wave (vmcnt accounting)
        float* const orow = outg + ((size_t)h * WW) * COUT;
#pragma unroll
        for (int mi = 0; mi < 2; ++mi) {
            const int f0 = fm + mi * 16 + hi * 4;
#pragma unroll
            for (int nj = 0; nj < 2; ++nj) {
                const int w = wnb + nj * 16 + lo;
                if (w < WW) {
                    f32x4 oo = acc[mi][nj];
                    oo[0] += bvv[mi].x; oo[1] += bvv[mi].y;
                    oo[2] += bvv[mi].z; oo[3] += bvv[mi].w;
                    *reinterpret_cast<f32x4*>(orow + (size_t)w * COUT + f0) = oo;
                }
            }
        }
    }
#undef STAGE
#undef CVTROW
}

// ---------------- launcher ----------------
extern "C" void kernel_launch(void* const* d_in, const int* in_sizes, int n_in,
                              void* d_out, int out_size, void* d_ws, size_t ws_size,
                              hipStream_t stream) {
    const float* x    = (const float*)d_in[0];
    const float* krn  = (const float*)d_in[1];
    const float* bias = (const float*)d_in[2];
    float* out = (float*)d_out;

    const int blocks = NB * 8 * NG;  // 1024
    groupconv_onew_kernel<<<blocks, 256, 0, stream>>>(x, krn, bias, out);
}